// Round 7
// baseline (263.987 us; speedup 1.0000x reference)
//
#include <hip/hip_runtime.h>
#include <hip/hip_cooperative_groups.h>

namespace cg = cooperative_groups;

// Problem constants (M, B, D = 32, 64, 8192)
#define Mh 32
#define Bh 64
#define Dh 8192

#define KCH 512                   // gram K-chunk per tile
#define NCH (Dh / KCH)            // 16 k-chunks
#define NT  (Bh * NCH)            // 1024 gram tiles
#define CT  (Bh * 8)              // 512 combine tiles (1024-float d-chunks)

// Workspace layout (float offsets), ~8.7 MB. No atomics -> no memset.
#define OFF_CY   0                          // [64][32]  g * a_i
#define OFF_CS   (OFF_CY + 64 * 32)         // [64][32]  b_i - a_i
#define OFF_G    (OFF_CS + 64 * 32)         // [64]
#define OFF_PART (OFF_G + 64)               // PSY[tile][1024], then PYY
#define PARTF    (NT * 1024)
#define OFF_VPS  (OFF_PART + 2 * PARTF)     // [tile][32]
#define OFF_VPY  (OFF_VPS + NT * 32)
#define WS_END   (OFF_VPY + NT * 32)

typedef __attribute__((ext_vector_type(8)))  __bf16 bf16x8;
typedef __attribute__((ext_vector_type(16))) float  f32x16;
typedef __attribute__((address_space(1))) const unsigned int gu32;
typedef __attribute__((address_space(3))) unsigned int lu32;

__device__ __forceinline__ float dot4(const float4 a, const float4 b)
{ return a.x * b.x + a.y * b.y + a.z * b.z + a.w * b.w; }

// fp32x8 -> bf16 hi/lo split: x ~= hi + lo with |err| ~ 2^-18 |x|
__device__ __forceinline__ void split8(const float4 a, const float4 b,
                                       bf16x8& h, bf16x8& lo)
{
    const float x[8] = {a.x, a.y, a.z, a.w, b.x, b.y, b.z, b.w};
    #pragma unroll
    for (int e = 0; e < 8; ++e) {
        h[e]  = (__bf16)x[e];
        lo[e] = (__bf16)(x[e] - (float)h[e]);
    }
}

// Shared-memory block reused by all phases (33.8 KB -> 4 blocks/CU by LDS).
struct SMem {
    float sF[2][32][64];   // double-buffered s stage (16 KB)
    float yF[2][32][64];   // double-buffered y stage (16 KB)
    float fR[4][64];       // per-wave vs/vy partials; cy/cs in phase 3
};

// ---------------------------------------------------------------------------
// Phase 1 tile: Gram partials for (b, kc) over K=[kc*512, +512).
// 2-deep global_load_lds pipeline: STAGE(st+2) issued right after the
// barrier that frees its buffer -> one 16 KB stage always in flight during
// compute; the barrier's vmcnt(0) drain waits on loads that already had a
// full compute phase to land. Round-6 lesson: without this structure the
// compiler (at default 64-VGPR occupancy target) sinks loads next to uses.
// Fragment facts (r3-r6 harness-verified): A-frag == B-frag lane map for
// mfma_f32_32x32x16_bf16 (lane l = row l&31, 8 k at 8*(l>>5)); C/D map
// col=l&31, row=(rr&3)+8*(rr>>2)+4*(l>>5). Swizzle per rule 21: linear LDS
// dest + XOR(i&15) pre-swizzled GLOBAL source + same XOR on LDS reads.
// ---------------------------------------------------------------------------
__device__ __forceinline__ void gram_tile(
    const int tile, const float* __restrict__ s, const float* __restrict__ y,
    const float* __restrict__ frc, float* __restrict__ ws, SMem& sm)
{
    const int t  = threadIdx.x;
    const int w  = t >> 6, l = t & 63;
    const int r  = l & 31, h = l >> 5;
    const int lr = l >> 4, s16 = l & 15;
    const int rx = r & 15;
    const int ga = (w << 2) + (h << 1);     // granule base: k-off (16w+8h)/4

    const int b = tile & 63, kc = tile >> 6;
    const size_t k0 = (size_t)kc * KCH;

    f32x16 accSY = {}, accYY = {};
    float avs = 0.f, avy = 0.f;

    auto stage = [&](int p, int st) {
        #pragma unroll
        for (int o = 0; o < 2; ++o) {
            const int rb = (w << 3) + (o << 2);      // wave stages rows rb..rb+3
            const int i  = rb + lr;
            const int g  = s16 ^ (i & 15);           // pre-swizzled global granule
            const size_t go = ((size_t)i * Bh + b) * Dh + k0 + ((size_t)st << 6) + (g << 2);
            __builtin_amdgcn_global_load_lds((gu32*)(s + go), (lu32*)&sm.sF[p][rb][0], 16, 0, 0);
            __builtin_amdgcn_global_load_lds((gu32*)(y + go), (lu32*)&sm.yF[p][rb][0], 16, 0, 0);
        }
    };

    const float* fp = frc + (size_t)b * Dh + k0 + (w << 4) + (h << 3);

    stage(0, 0);
    stage(1, 1);
    float4 fa[2], fb[2];
    fa[0] = *(const float4*)(fp);
    fb[0] = *(const float4*)(fp + 4);
    __syncthreads();                       // both prologue stages resident

    #pragma unroll
    for (int st = 0; st < 8; ++st) {       // 8 x 64-k steps = 512 K
        const int cur = st & 1;
        if (st < 7) {                      // frc prefetch for next step
            fa[cur ^ 1] = *(const float4*)(fp + ((st + 1) << 6));
            fb[cur ^ 1] = *(const float4*)(fp + ((st + 1) << 6) + 4);
        }
        const float4 sa = *(const float4*)&sm.sF[cur][r][(ga ^ rx) << 2];
        const float4 sb = *(const float4*)&sm.sF[cur][r][((ga + 1) ^ rx) << 2];
        const float4 ya = *(const float4*)&sm.yF[cur][r][(ga ^ rx) << 2];
        const float4 yb = *(const float4*)&sm.yF[cur][r][((ga + 1) ^ rx) << 2];
        avs += dot4(sa, fa[cur]) + dot4(sb, fb[cur]);   // exact-fp32 frc dots
        avy += dot4(ya, fa[cur]) + dot4(yb, fb[cur]);
        bf16x8 aSH, aSL, aYH, aYL;
        split8(sa, sb, aSH, aSL);
        split8(ya, yb, aYH, aYL);
        accSY = __builtin_amdgcn_mfma_f32_32x32x16_bf16(aSH, aYH, accSY, 0, 0, 0);
        accYY = __builtin_amdgcn_mfma_f32_32x32x16_bf16(aYH, aYH, accYY, 0, 0, 0);
        accSY = __builtin_amdgcn_mfma_f32_32x32x16_bf16(aSH, aYL, accSY, 0, 0, 0);
        accYY = __builtin_amdgcn_mfma_f32_32x32x16_bf16(aYH, aYL, accYY, 0, 0, 0);
        accSY = __builtin_amdgcn_mfma_f32_32x32x16_bf16(aSL, aYH, accSY, 0, 0, 0);
        accYY = __builtin_amdgcn_mfma_f32_32x32x16_bf16(aYL, aYH, accYY, 0, 0, 0);
        __syncthreads();                   // frees buf[cur]; drains in-flight stage
        if (st < 6) stage(cur, st + 2);    // refill freed buffer for st+2
    }

    // vs/vy: lanes l and l+32 hold the two 8-k halves of row r
    avs += __shfl_xor(avs, 32);
    avy += __shfl_xor(avy, 32);

    // cross-wave reduction through the (now free) staging LDS
    float* RS = &sm.sF[0][0][0];           // 4 waves x 1024 (Wsy)
    float* RY = &sm.yF[0][0][0];           // 4 waves x 1024 (Wyy)
    #pragma unroll
    for (int rr = 0; rr < 16; ++rr) {
        const int i = (rr & 3) + ((rr >> 2) << 3) + (h << 2);
        RS[w * 1024 + i * 32 + r] = accSY[rr];
        RY[w * 1024 + i * 32 + r] = accYY[rr];
    }
    if (h == 0) { sm.fR[w][r] = avs; sm.fR[w][32 + r] = avy; }
    __syncthreads();

    float* PS = ws + OFF_PART + (size_t)tile * 1024;
    float* PY = ws + OFF_PART + PARTF + (size_t)tile * 1024;
    const int e4 = t << 2;
    float4 a0 = *(const float4*)&RS[e4];
    const float4 a1 = *(const float4*)&RS[1024 + e4];
    const float4 a2 = *(const float4*)&RS[2048 + e4];
    const float4 a3 = *(const float4*)&RS[3072 + e4];
    a0.x += a1.x + a2.x + a3.x;  a0.y += a1.y + a2.y + a3.y;
    a0.z += a1.z + a2.z + a3.z;  a0.w += a1.w + a2.w + a3.w;
    *(float4*)&PS[e4] = a0;
    float4 c0 = *(const float4*)&RY[e4];
    const float4 c1 = *(const float4*)&RY[1024 + e4];
    const float4 c2 = *(const float4*)&RY[2048 + e4];
    const float4 c3 = *(const float4*)&RY[3072 + e4];
    c0.x += c1.x + c2.x + c3.x;  c0.y += c1.y + c2.y + c3.y;
    c0.z += c1.z + c2.z + c3.z;  c0.w += c1.w + c2.w + c3.w;
    *(float4*)&PY[e4] = c0;
    if (t < 32) {
        ws[OFF_VPS + (size_t)tile * 32 + t] =
            sm.fR[0][t] + sm.fR[1][t] + sm.fR[2][t] + sm.fR[3][t];
    } else if (t < 64) {
        const int i2 = t - 32;
        ws[OFF_VPY + (size_t)tile * 32 + i2] =
            sm.fR[0][32 + i2] + sm.fR[1][32 + i2] + sm.fR[2][32 + i2] + sm.fR[3][32 + i2];
    }
    __syncthreads();                       // LDS free before next tile's stage
}

// ---------------------------------------------------------------------------
// Phase 2: reduce the 16 k-chunk partials into LDS, then the per-b M=32 f64
// recursion (wave 0). Gram rows read directly from LDS (saves ~96 VGPR vs
// register arrays so the fused kernel's occupancy isn't recursion-bound).
// ---------------------------------------------------------------------------
__device__ __forceinline__ void recur_b(const int b, float* __restrict__ ws, SMem& sm)
{
    const int t = threadIdx.x;
    float* WSY = &sm.sF[0][0][0];
    float* WYY = &sm.yF[0][0][0];

    const int e4 = t << 2;
    float4 a = make_float4(0.f, 0.f, 0.f, 0.f);
    float4 c = make_float4(0.f, 0.f, 0.f, 0.f);
    #pragma unroll
    for (int kc = 0; kc < NCH; ++kc) {
        const size_t o = ((size_t)(kc * 64 + b)) * 1024 + e4;
        const float4 v = *(const float4*)&ws[OFF_PART + o];
        const float4 u = *(const float4*)&ws[OFF_PART + PARTF + o];
        a.x += v.x; a.y += v.y; a.z += v.z; a.w += v.w;
        c.x += u.x; c.y += u.y; c.z += u.z; c.w += u.w;
    }
    *(float4*)&WSY[e4] = a;
    *(float4*)&WYY[e4] = c;
    if (t < 64) {
        const int i = t & 31;
        const float* PV = ws + (t < 32 ? OFF_VPS : OFF_VPY);
        float acc = 0.f;
        #pragma unroll
        for (int kc = 0; kc < NCH; ++kc)
            acc += PV[((size_t)(kc * 64 + b)) * 32 + i];
        sm.fR[t < 32 ? 0 : 1][i] = acc;
    }
    __syncthreads();

    if (t < 64) {
        const int i = t & 31;              // lanes 32..63 mirror (writes guarded)
        const double r = 1.0 / (double)WSY[i * 32 + i];
        double acc2 = -(double)sm.fR[0][i];
        double a_val = 0.0;
        #pragma unroll
        for (int j = 31; j >= 0; --j) {    // backward scan
            const double aj = __shfl(r, j) * __shfl(acc2, j);
            if (i == j) a_val = aj;
            if (i < j)  acc2 -= aj * (double)WSY[i * 32 + j];
        }
        const double g = (double)WSY[31 * 32 + 31] / (double)WYY[31 * 32 + 31];
        double u = -(double)sm.fR[1][i];
        #pragma unroll
        for (int j = 0; j < 32; ++j)
            u -= __shfl(a_val, j) * (double)WYY[i * 32 + j];
        u *= g;
        double tt = u;
        double b_val = 0.0;
        #pragma unroll
        for (int j = 0; j < 32; ++j) {     // forward scan
            const double bj = __shfl(r, j) * __shfl(tt, j);
            if (i == j) b_val = bj;
            const double dj = __shfl(a_val, j) - bj;
            if (i > j) tt += dj * (double)WSY[j * 32 + i];
        }
        if (t < 32) {
            ws[OFF_CY + b * 32 + i] = (float)(g * a_val);
            ws[OFF_CS + b * 32 + i] = (float)(b_val - a_val);
        }
        if (t == 0) ws[OFF_G + b] = (float)g;
    }
    __syncthreads();
}

// ---------------------------------------------------------------------------
// Phase 3 tile: out[b,d] = g*frc + sum_i cy[i]*y[i,b,d] + cs[i]*s[i,b,d]
// for d in [dc*1024, +1024). s,y are L3-hot (phase 1 just streamed them).
// ---------------------------------------------------------------------------
__device__ __forceinline__ void combine_tile(
    const int tile, const float* __restrict__ s, const float* __restrict__ y,
    const float* __restrict__ frc, const float* __restrict__ ws,
    float* __restrict__ out, SMem& sm)
{
    const int t = threadIdx.x;
    const int b = tile & 63, dc = tile >> 6;
    __syncthreads();                       // protect fR reuse across tiles
    if (t < 32) {
        sm.fR[2][t] = ws[OFF_CY + b * 32 + t];
        sm.fR[3][t] = ws[OFF_CS + b * 32 + t];
    }
    __syncthreads();

    const int d = (dc << 10) + (t << 2);
    const float g = ws[OFF_G + b];
    const float4 fv = *(const float4*)(frc + (size_t)b * Dh + d);
    float4 acc = make_float4(g * fv.x, g * fv.y, g * fv.z, g * fv.w);
    #pragma unroll 8
    for (int i = 0; i < 32; ++i) {
        const float4 yv = *(const float4*)(y + ((size_t)i * Bh + b) * Dh + d);
        const float4 sv = *(const float4*)(s + ((size_t)i * Bh + b) * Dh + d);
        const float a1 = sm.fR[2][i], a2 = sm.fR[3][i];
        acc.x += a1 * yv.x + a2 * sv.x;
        acc.y += a1 * yv.y + a2 * sv.y;
        acc.z += a1 * yv.z + a2 * sv.z;
        acc.w += a1 * yv.w + a2 * sv.w;
    }
    *(float4*)(out + (size_t)b * Dh + d) = acc;
}

// ---------------------------------------------------------------------------
// Fused cooperative kernel: gram -> grid.sync -> recur -> grid.sync -> combine
// Persistent blocks so any co-resident grid size works.
// ---------------------------------------------------------------------------
__global__ __launch_bounds__(256) void fused_kernel(
    const float* __restrict__ s, const float* __restrict__ y,
    const float* __restrict__ frc, float* __restrict__ ws,
    float* __restrict__ out)
{
    __shared__ SMem sm;
    for (int tile = blockIdx.x; tile < NT; tile += gridDim.x)
        gram_tile(tile, s, y, frc, ws, sm);
    cg::this_grid().sync();
    if (blockIdx.x < 64)
        recur_b(blockIdx.x, ws, sm);
    cg::this_grid().sync();
    for (int tile = blockIdx.x; tile < CT; tile += gridDim.x)
        combine_tile(tile, s, y, frc, ws, out, sm);
}

// Fallback: identical math as three stream-ordered kernels (no grid.sync).
__global__ __launch_bounds__(256) void p1_kernel(
    const float* __restrict__ s, const float* __restrict__ y,
    const float* __restrict__ frc, float* __restrict__ ws)
{ __shared__ SMem sm; gram_tile(blockIdx.x, s, y, frc, ws, sm); }

__global__ __launch_bounds__(256) void p2_kernel(float* __restrict__ ws)
{ __shared__ SMem sm; recur_b(blockIdx.x, ws, sm); }

__global__ __launch_bounds__(256) void p3_kernel(
    const float* __restrict__ s, const float* __restrict__ y,
    const float* __restrict__ frc, const float* __restrict__ ws,
    float* __restrict__ out)
{ __shared__ SMem sm; combine_tile(blockIdx.x, s, y, frc, ws, out, sm); }

extern "C" void kernel_launch(void* const* d_in, const int* in_sizes, int n_in,
                              void* d_out, int out_size, void* d_ws, size_t ws_size,
                              hipStream_t stream)
{
    const float* s   = (const float*)d_in[0];
    const float* y   = (const float*)d_in[1];
    const float* frc = (const float*)d_in[2];
    float* out = (float*)d_out;
    float* ws  = (float*)d_ws;

    static int coop  = -1;   // -1 unknown, 0 unusable, 1 usable
    static int gridN = 0;
    if (coop < 0) {
        int dev = 0;
        hipGetDevice(&dev);
        hipDeviceProp_t prop;
        int maxB = 0;
        if (hipGetDeviceProperties(&prop, dev) == hipSuccess &&
            hipOccupancyMaxActiveBlocksPerMultiprocessor(&maxB, fused_kernel, 256, 0) == hipSuccess &&
            prop.cooperativeLaunch && maxB >= 1) {
            gridN = maxB * prop.multiProcessorCount;
            if (gridN > NT) gridN = NT;
            coop = (gridN >= 64) ? 1 : 0;
        } else {
            coop = 0;
        }
    }

    bool done = false;
    if (coop == 1 && ws_size >= (size_t)WS_END * sizeof(float)) {
        void* args[] = {(void*)&s, (void*)&y, (void*)&frc, (void*)&ws, (void*)&out};
        if (hipLaunchCooperativeKernel((const void*)fused_kernel, dim3(gridN),
                                       dim3(256), args, 0, stream) == hipSuccess) {
            done = true;
        } else {
            (void)hipGetLastError();   // clear; permanently fall back
            coop = 0;
        }
    }
    if (!done) {
        p1_kernel<<<dim3(NT), dim3(256), 0, stream>>>(s, y, frc, ws);
        p2_kernel<<<dim3(Bh), dim3(256), 0, stream>>>(ws);
        p3_kernel<<<dim3(CT), dim3(256), 0, stream>>>(s, y, frc, ws, out);
    }
}

// Round 8
// 183.574 us; speedup vs baseline: 1.4380x; 1.4380x over previous
//
#include <hip/hip_runtime.h>

// Problem constants (M, B, D = 32, 64, 8192)
#define Mh 32
#define Bh 64
#define Dh 8192

// ---- workspace layout (float offsets) ----
#define OFF_WSY 0                       // [64][32][32] (atomic tier only)
#define OFF_WYY (64 * 1024)
#define OFF_VS  (2 * 64 * 1024)        // [64][32]     (atomic tier only)
#define OFF_VY  (OFF_VS + 64 * 32)
#define OFF_CY  (OFF_VY + 64 * 32)     // [64][32]  g * a_i
#define OFF_CS  (OFF_CY + 64 * 32)     // [64][32]  b_i - a_i
#define OFF_G   (OFF_CS + 64 * 32)     // [64]
#define WS_ZERO_FLOATS OFF_CY          // atomic-tier zero region
#define OFF_PART (OFF_G + 64)
// Slabs, transposed for contiguous recur reads (NCHX = k-chunks = 64 or 32):
//   PSY[b][kc][1024] at OFF_PART;  PYY at +PARTF(NCHX)
//   VPS[b][kc][32]   at OFF_VPS;   VPY at +64*NCHX*32
#define PARTF(N)   (64 * (N) * 1024)
#define OFF_VPS(N) (OFF_PART + 2 * PARTF(N))
#define OFF_VPY(N) (OFF_VPS(N) + 64 * (N) * 32)
#define WS_END(N)  (OFF_VPY(N) + 64 * (N) * 32)

typedef __attribute__((ext_vector_type(8)))  __bf16 bf16x8;
typedef __attribute__((ext_vector_type(16))) float  f32x16;
typedef __attribute__((address_space(1))) const unsigned int gu32;
typedef __attribute__((address_space(3))) unsigned int lu32;

__device__ __forceinline__ float dot4(const float4 a, const float4 b)
{ return a.x * b.x + a.y * b.y + a.z * b.z + a.w * b.w; }

// fp32x8 -> bf16 hi/lo split: x ~= hi + lo with |err| ~ 2^-18 |x|
__device__ __forceinline__ void split8(const float4 a, const float4 b,
                                       bf16x8& h, bf16x8& lo)
{
    const float x[8] = {a.x, a.y, a.z, a.w, b.x, b.y, b.z, b.w};
    #pragma unroll
    for (int e = 0; e < 8; ++e) {
        h[e]  = (__bf16)x[e];
        lo[e] = (__bf16)(x[e] - (float)h[e]);
    }
}

// ---------------------------------------------------------------------------
// Tier-1 Kernel A: KCH=128 burst gram. grid = 64 b x 64 kc = 4096 blocks.
// r5 evidence: the KCH=256 burst gram (46 us) was residency-capped: 64 KB
// LDS -> 2 blocks/CU max, measured 1.4 (occ 17.6%); all waves drain the
// burst together with no sibling cover. Halving the tile: LDS 33 KB -> 4
// blocks/CU, 4096 blocks -> natural desync, 16 waves/CU. Structure is
// r5-proven: issue ALL global_load_lds (8/thread) then ONE drain; compute
// loop has no barriers. Swizzle per rule 21 (linear LDS dest, XOR(i&15)
// pre-swizzled global source, same XOR on reads; conflict-free per r5 PMC).
// Wave k-ownership: waves 0,1 -> stage 0 (k 0..63), waves 2,3 -> stage 1;
// within stage, (w&1) picks the 32-k half; 2 MFMA steps of K=16.
// Fragment map (r3-r6 harness-verified): A==B lane map, lane l = row l&31,
// 8 k at 8*(l>>5); C/D col=l&31, row=(rr&3)+8*(rr>>2)+4*(l>>5).
// No atomics anywhere; vs/vy go to slab. No min-waves clamp (r1 lesson).
// ---------------------------------------------------------------------------
__global__ __launch_bounds__(256) void gram128_kernel(
    const float* __restrict__ s, const float* __restrict__ y,
    const float* __restrict__ frc, float* __restrict__ ws)
{
    __shared__ __align__(16) float sF[2][32][64];   // 16 KB
    __shared__ __align__(16) float yF[2][32][64];   // 16 KB
    __shared__ float fR[4][64];                     // per-wave vs/vy partials

    const int bid = blockIdx.x;
    const int b  = bid >> 6;
    const int kc = bid & 63;
    const size_t k0 = (size_t)kc << 7;              // *128
    const int t = threadIdx.x;
    const int w = t >> 6, l = t & 63;
    const int lr = l >> 4, s16 = l & 15;

    // ---- burst: 8 global_load_lds, one drain ----
    #pragma unroll
    for (int st = 0; st < 2; ++st) {
        #pragma unroll
        for (int o = 0; o < 2; ++o) {
            const int rb = (w << 3) + (o << 2);     // wave-uniform row base
            const int i  = rb + lr;
            const int g  = s16 ^ (i & 15);          // pre-swizzled granule
            const size_t go = ((size_t)i * Bh + b) * Dh + k0 + (st << 6) + (g << 2);
            __builtin_amdgcn_global_load_lds((gu32*)(s + go), (lu32*)&sF[st][rb][0], 16, 0, 0);
            __builtin_amdgcn_global_load_lds((gu32*)(y + go), (lu32*)&yF[st][rb][0], 16, 0, 0);
        }
    }

    const int r = l & 31, h = l >> 5;
    const int sidx = w >> 1;
    const int rx = r & 15;
    // frc slice for this lane: stage sidx, half (w&1), 8-k sub h
    const float* fp = frc + (size_t)b * Dh + k0 + (sidx << 6) + ((w & 1) << 5) + (h << 3);
    const float4 fa0 = *(const float4*)(fp);
    const float4 fb0 = *(const float4*)(fp + 4);
    const float4 fa1 = *(const float4*)(fp + 16);
    const float4 fb1 = *(const float4*)(fp + 20);

    __syncthreads();                                // single burst drain

    f32x16 accSY = {}, accYY = {};
    float avs = 0.f, avy = 0.f;

    #pragma unroll
    for (int j = 0; j < 2; ++j) {                   // two K=16 MFMA steps
        const int gb = ((w & 1) << 3) + (j << 2) + (h << 1);
        const float4 sa = *(const float4*)&sF[sidx][r][(gb ^ rx) << 2];
        const float4 sb = *(const float4*)&sF[sidx][r][((gb + 1) ^ rx) << 2];
        const float4 ya = *(const float4*)&yF[sidx][r][(gb ^ rx) << 2];
        const float4 yb = *(const float4*)&yF[sidx][r][((gb + 1) ^ rx) << 2];
        const float4 fa = j ? fa1 : fa0, fb = j ? fb1 : fb0;
        avs += dot4(sa, fa) + dot4(sb, fb);         // exact-fp32 frc dots
        avy += dot4(ya, fa) + dot4(yb, fb);
        bf16x8 aSH, aSL, aYH, aYL;
        split8(sa, sb, aSH, aSL);
        split8(ya, yb, aYH, aYL);
        accSY = __builtin_amdgcn_mfma_f32_32x32x16_bf16(aSH, aYH, accSY, 0, 0, 0);
        accYY = __builtin_amdgcn_mfma_f32_32x32x16_bf16(aYH, aYH, accYY, 0, 0, 0);
        accSY = __builtin_amdgcn_mfma_f32_32x32x16_bf16(aSH, aYL, accSY, 0, 0, 0);
        accYY = __builtin_amdgcn_mfma_f32_32x32x16_bf16(aYH, aYL, accYY, 0, 0, 0);
        accSY = __builtin_amdgcn_mfma_f32_32x32x16_bf16(aSL, aYH, accSY, 0, 0, 0);
        accYY = __builtin_amdgcn_mfma_f32_32x32x16_bf16(aYL, aYH, accYY, 0, 0, 0);
    }

    // row-r vs/vy: lane + its h-partner cover this wave's 32 k
    avs += __shfl_xor(avs, 32);
    avy += __shfl_xor(avy, 32);
    if (h == 0) { fR[w][r] = avs; fR[w][32 + r] = avy; }

    __syncthreads();             // ALL sF/yF reads done before reuse (race fix)

    float* RS = &sF[0][0][0];    // 4 waves x 1024 floats (Wsy partials)
    float* RY = &yF[0][0][0];
    #pragma unroll
    for (int rr = 0; rr < 16; ++rr) {
        const int i = (rr & 3) + ((rr >> 2) << 3) + (h << 2);
        RS[w * 1024 + i * 32 + r] = accSY[rr];
        RY[w * 1024 + i * 32 + r] = accYY[rr];
    }
    __syncthreads();

    float* PS = ws + OFF_PART + (size_t)bid * 1024;            // [b][kc]
    float* PY = PS + PARTF(64);
    const int e4 = t << 2;
    float4 a0 = *(const float4*)&RS[e4];
    const float4 a1 = *(const float4*)&RS[1024 + e4];
    const float4 a2 = *(const float4*)&RS[2048 + e4];
    const float4 a3 = *(const float4*)&RS[3072 + e4];
    a0.x += a1.x + a2.x + a3.x;  a0.y += a1.y + a2.y + a3.y;
    a0.z += a1.z + a2.z + a3.z;  a0.w += a1.w + a2.w + a3.w;
    *(float4*)&PS[e4] = a0;
    float4 c0 = *(const float4*)&RY[e4];
    const float4 c1 = *(const float4*)&RY[1024 + e4];
    const float4 c2 = *(const float4*)&RY[2048 + e4];
    const float4 c3 = *(const float4*)&RY[3072 + e4];
    c0.x += c1.x + c2.x + c3.x;  c0.y += c1.y + c2.y + c3.y;
    c0.z += c1.z + c2.z + c3.z;  c0.w += c1.w + c2.w + c3.w;
    *(float4*)&PY[e4] = c0;
    if (t < 32) {
        ws[OFF_VPS(64) + (size_t)bid * 32 + t] =
            fR[0][t] + fR[1][t] + fR[2][t] + fR[3][t];
    } else if (t < 64) {
        const int i2 = t - 32;
        ws[OFF_VPY(64) + (size_t)bid * 32 + i2] =
            fR[0][32 + i2] + fR[1][32 + i2] + fR[2][32 + i2] + fR[3][32 + i2];
    }
}

// ---------------------------------------------------------------------------
// Tier-2/3 Kernel A: KCH=256 burst gram (r5-proven, 46 us), transposed slab
// + slab vs/vy (SLAB=1) or atomics (SLAB=0). grid = 64 b x 32 kc.
// ---------------------------------------------------------------------------
template <int SLAB>
__global__ __launch_bounds__(256) void gram256_kernel(
    const float* __restrict__ s, const float* __restrict__ y,
    const float* __restrict__ frc, float* __restrict__ ws)
{
    __shared__ __align__(16) float sF[4][32][64];   // 32 KB
    __shared__ __align__(16) float yF[4][32][64];   // 32 KB

    const int b  = blockIdx.x & 63;
    const int ch = blockIdx.x >> 6;
    const size_t k0 = (size_t)ch << 8;
    const int t = threadIdx.x;
    const int w = t >> 6, l = t & 63;

    {   // burst: 16 global_load_lds, one drain
        const int lr = l >> 4, s16 = l & 15;
        #pragma unroll
        for (int st = 0; st < 4; ++st) {
            #pragma unroll
            for (int o = 0; o < 2; ++o) {
                const int rb = (w << 3) + (o << 2);
                const int i = rb + lr;
                const int g = s16 ^ (i & 15);
                const size_t go = ((size_t)i * Bh + b) * Dh + k0 + (st << 6) + (g << 2);
                __builtin_amdgcn_global_load_lds((gu32*)(s + go), (lu32*)&sF[st][rb][0], 16, 0, 0);
                __builtin_amdgcn_global_load_lds((gu32*)(y + go), (lu32*)&yF[st][rb][0], 16, 0, 0);
            }
        }
    }

    const int i0 = t >> 4, i1 = i0 + 16, k4 = t & 15;
    const float* fp = frc + (size_t)b * Dh + k0 + (k4 << 2);
    float4 fv[4];
    #pragma unroll
    for (int st = 0; st < 4; ++st) fv[st] = *(const float4*)(fp + st * 64);

    __syncthreads();

    f32x16 accSY = {}, accYY = {};
    float avs0 = 0.f, avs1 = 0.f, avy0 = 0.f, avy1 = 0.f;
    const int row = l & 31, h = l >> 5;
    const int g0 = (w << 2) + (h << 1);
    const int rx = row & 15;
    const int x0 = i0 & 15, x1 = i1 & 15;

    #pragma unroll
    for (int st = 0; st < 4; ++st) {
        const float4 sa = *(const float4*)&sF[st][row][(g0 ^ rx) << 2];
        const float4 sb = *(const float4*)&sF[st][row][((g0 + 1) ^ rx) << 2];
        const float4 ya = *(const float4*)&yF[st][row][(g0 ^ rx) << 2];
        const float4 yb = *(const float4*)&yF[st][row][((g0 + 1) ^ rx) << 2];
        bf16x8 aSH, aSL, aYH, aYL;
        split8(sa, sb, aSH, aSL);
        split8(ya, yb, aYH, aYL);
        accSY = __builtin_amdgcn_mfma_f32_32x32x16_bf16(aSH, aYH, accSY, 0, 0, 0);
        accYY = __builtin_amdgcn_mfma_f32_32x32x16_bf16(aYH, aYH, accYY, 0, 0, 0);
        accSY = __builtin_amdgcn_mfma_f32_32x32x16_bf16(aSH, aYL, accSY, 0, 0, 0);
        accYY = __builtin_amdgcn_mfma_f32_32x32x16_bf16(aYH, aYL, accYY, 0, 0, 0);
        accSY = __builtin_amdgcn_mfma_f32_32x32x16_bf16(aSL, aYH, accSY, 0, 0, 0);
        accYY = __builtin_amdgcn_mfma_f32_32x32x16_bf16(aYL, aYH, accYY, 0, 0, 0);

        const float4 s0v = *(const float4*)&sF[st][i0][(k4 ^ x0) << 2];
        const float4 y0v = *(const float4*)&yF[st][i0][(k4 ^ x0) << 2];
        const float4 s1v = *(const float4*)&sF[st][i1][(k4 ^ x1) << 2];
        const float4 y1v = *(const float4*)&yF[st][i1][(k4 ^ x1) << 2];
        const float4 f = fv[st];
        avs0 += dot4(s0v, f);  avy0 += dot4(y0v, f);
        avs1 += dot4(s1v, f);  avy1 += dot4(y1v, f);
    }

    #pragma unroll
    for (int m = 1; m < 16; m <<= 1) {
        avs0 += __shfl_xor(avs0, m);
        avs1 += __shfl_xor(avs1, m);
        avy0 += __shfl_xor(avy0, m);
        avy1 += __shfl_xor(avy1, m);
    }
    const int g16 = t & 15;
    const size_t tile = (size_t)b * 32 + ch;
    if (SLAB) {
        if      (g16 == 0) ws[OFF_VPS(32) + tile * 32 + i0] = avs0;
        else if (g16 == 1) ws[OFF_VPS(32) + tile * 32 + i1] = avs1;
        else if (g16 == 2) ws[OFF_VPY(32) + tile * 32 + i0] = avy0;
        else if (g16 == 3) ws[OFF_VPY(32) + tile * 32 + i1] = avy1;
    } else {
        if      (g16 == 0) unsafeAtomicAdd(&ws[OFF_VS + b * 32 + i0], avs0);
        else if (g16 == 1) unsafeAtomicAdd(&ws[OFF_VS + b * 32 + i1], avs1);
        else if (g16 == 2) unsafeAtomicAdd(&ws[OFF_VY + b * 32 + i0], avy0);
        else if (g16 == 3) unsafeAtomicAdd(&ws[OFF_VY + b * 32 + i1], avy1);
    }

    __syncthreads();             // all sF/yF reads done before reuse (race fix)
    float* RS = &sF[0][0][0];
    float* RY = &yF[0][0][0];
    #pragma unroll
    for (int rr = 0; rr < 16; ++rr) {
        const int i = (rr & 3) + ((rr >> 2) << 3) + (h << 2);
        RS[w * 1024 + i * 32 + row] = accSY[rr];
        RY[w * 1024 + i * 32 + row] = accYY[rr];
    }
    __syncthreads();

    if (SLAB) {
        float* PS = ws + OFF_PART + tile * 1024;
        float* PY = PS + PARTF(32);
        const int e4 = t << 2;
        float4 a0 = *(const float4*)&RS[e4];
        const float4 a1 = *(const float4*)&RS[1024 + e4];
        const float4 a2 = *(const float4*)&RS[2048 + e4];
        const float4 a3 = *(const float4*)&RS[3072 + e4];
        a0.x += a1.x + a2.x + a3.x;  a0.y += a1.y + a2.y + a3.y;
        a0.z += a1.z + a2.z + a3.z;  a0.w += a1.w + a2.w + a3.w;
        *(float4*)&PS[e4] = a0;
        float4 c0 = *(const float4*)&RY[e4];
        const float4 c1 = *(const float4*)&RY[1024 + e4];
        const float4 c2 = *(const float4*)&RY[2048 + e4];
        const float4 c3 = *(const float4*)&RY[3072 + e4];
        c0.x += c1.x + c2.x + c3.x;  c0.y += c1.y + c2.y + c3.y;
        c0.z += c1.z + c2.z + c3.z;  c0.w += c1.w + c2.w + c3.w;
        *(float4*)&PY[e4] = c0;
    } else {
        float* WSY = ws + OFF_WSY + b * 1024;
        float* WYY = ws + OFF_WYY + b * 1024;
        for (int e = t; e < 1024; e += 256) {
            unsafeAtomicAdd(&WSY[e], RS[e] + RS[1024 + e] + RS[2048 + e] + RS[3072 + e]);
            unsafeAtomicAdd(&WYY[e], RY[e] + RY[1024 + e] + RY[2048 + e] + RY[3072 + e]);
        }
    }
}

// ---------------------------------------------------------------------------
// Kernel B: slab-reduce (contiguous per-b reads thanks to [b][kc] layout)
// into LDS, then the per-b M=32 f64 recursion (register-array form, r5).
// grid = 64 blocks x 256 threads.
// ---------------------------------------------------------------------------
template <int NCHX, int SLAB>
__global__ __launch_bounds__(256) void recur_kernel(float* __restrict__ ws)
{
    __shared__ float WSY_l[1024], WYY_l[1024];
    __shared__ float vsL[32], vyL[32];
    const int b = blockIdx.x;
    const int t = threadIdx.x;

    if (SLAB) {
        const int e4 = t << 2;
        const float* PS = ws + OFF_PART + (size_t)b * NCHX * 1024;   // contiguous
        const float* PY = PS + PARTF(NCHX);
        float4 a = make_float4(0.f, 0.f, 0.f, 0.f);
        float4 c = make_float4(0.f, 0.f, 0.f, 0.f);
        #pragma unroll 8
        for (int kc = 0; kc < NCHX; ++kc) {
            const float4 v = *(const float4*)&PS[kc * 1024 + e4];
            const float4 u = *(const float4*)&PY[kc * 1024 + e4];
            a.x += v.x; a.y += v.y; a.z += v.z; a.w += v.w;
            c.x += u.x; c.y += u.y; c.z += u.z; c.w += u.w;
        }
        *(float4*)&WSY_l[e4] = a;
        *(float4*)&WYY_l[e4] = c;
        if (t < 64) {
            const int i = t & 31;
            const float* PV = ws + (t < 32 ? OFF_VPS(NCHX) : OFF_VPY(NCHX))
                               + (size_t)b * NCHX * 32;
            float acc = 0.f;
            #pragma unroll 8
            for (int kc = 0; kc < NCHX; ++kc) acc += PV[kc * 32 + i];
            (t < 32 ? vsL : vyL)[i] = acc;
        }
    } else {
        for (int e = t; e < 1024; e += 256) {
            WSY_l[e] = ws[OFF_WSY + b * 1024 + e];
            WYY_l[e] = ws[OFF_WYY + b * 1024 + e];
        }
        if (t < 32)      vsL[t] = ws[OFF_VS + b * 32 + t];
        else if (t < 64) vyL[t - 32] = ws[OFF_VY + b * 32 + (t - 32)];
    }
    __syncthreads();

    if (t < 64) {
        const int i = t & 31;   // lanes 32..63 mirror 0..31 (writes guarded)
        float row_sy[32], col_sy[32], row_yy[32];
        #pragma unroll
        for (int j = 0; j < 32; ++j) {
            row_sy[j] = WSY_l[i * 32 + j];
            col_sy[j] = WSY_l[j * 32 + i];
            row_yy[j] = WYY_l[i * 32 + j];
        }

        const double r = 1.0 / (double)row_sy[i];
        double acc = -(double)vsL[i];
        double a_val = 0.0;
        #pragma unroll
        for (int j = 31; j >= 0; --j) {                    // backward scan
            const double aj = __shfl(r, j) * __shfl(acc, j);
            if (i == j) a_val = aj;
            if (i < j)  acc -= aj * (double)row_sy[j];
        }

        const double g = (double)WSY_l[31 * 32 + 31] / (double)WYY_l[31 * 32 + 31];

        double u = -(double)vyL[i];
        #pragma unroll
        for (int j = 0; j < 32; ++j)
            u -= __shfl(a_val, j) * (double)row_yy[j];
        u *= g;

        double tt = u;
        double b_val = 0.0;
        #pragma unroll
        for (int j = 0; j < 32; ++j) {                     // forward scan
            const double bj = __shfl(r, j) * __shfl(tt, j);
            if (i == j) b_val = bj;
            const double dj = __shfl(a_val, j) - bj;
            if (i > j) tt += dj * (double)col_sy[j];
        }

        if (t < 32) {
            ws[OFF_CY + b * 32 + i] = (float)(g * a_val);
            ws[OFF_CS + b * 32 + i] = (float)(b_val - a_val);
        }
        if (t == 0) ws[OFF_G + b] = (float)g;
    }
}

// ---------------------------------------------------------------------------
// Kernel C (r5-verbatim, held constant this round so its counters surface
// once gram shrinks): grid = 64 b x 8 d-chunks, 1024 threads, 4-way i-split.
// ---------------------------------------------------------------------------
__global__ __launch_bounds__(1024) void combine_kernel(
    const float* __restrict__ s, const float* __restrict__ y,
    const float* __restrict__ frc, const float* __restrict__ ws,
    float* __restrict__ out)
{
    __shared__ float cy[32], cs[32];
    __shared__ float4 red[3][256];
    const int b  = blockIdx.x & 63;
    const int ch = blockIdx.x >> 6;
    const int t  = threadIdx.x;
    const int q  = t >> 8;          // quarter 0..3: i in [8q, 8q+8)
    const int tt = t & 255;
    if (t < 32) { cy[t] = ws[OFF_CY + b * 32 + t]; cs[t] = ws[OFF_CS + b * 32 + t]; }
    __syncthreads();

    const int d = ch * 1024 + (tt << 2);
    float4 acc = make_float4(0.f, 0.f, 0.f, 0.f);
    if (q == 0) {
        const float g = ws[OFF_G + b];
        const float4 fv = *(const float4*)(frc + (size_t)b * Dh + d);
        acc.x = g * fv.x; acc.y = g * fv.y; acc.z = g * fv.z; acc.w = g * fv.w;
    }
    const int ib = q << 3;
    #pragma unroll
    for (int i2 = 0; i2 < 8; ++i2) {
        const int i = ib + i2;
        const float4 yv = *(const float4*)(y + ((size_t)i * Bh + b) * Dh + d);
        const float4 sv = *(const float4*)(s + ((size_t)i * Bh + b) * Dh + d);
        const float a1 = cy[i], a2 = cs[i];
        acc.x += a1 * yv.x + a2 * sv.x;
        acc.y += a1 * yv.y + a2 * sv.y;
        acc.z += a1 * yv.z + a2 * sv.z;
        acc.w += a1 * yv.w + a2 * sv.w;
    }
    if (q) red[q - 1][tt] = acc;
    __syncthreads();
    if (q == 0) {
        const float4 r0 = red[0][tt], r1 = red[1][tt], r2 = red[2][tt];
        acc.x += r0.x + r1.x + r2.x;
        acc.y += r0.y + r1.y + r2.y;
        acc.z += r0.z + r1.z + r2.z;
        acc.w += r0.w + r1.w + r2.w;
        *(float4*)(out + (size_t)b * Dh + d) = acc;
    }
}

extern "C" void kernel_launch(void* const* d_in, const int* in_sizes, int n_in,
                              void* d_out, int out_size, void* d_ws, size_t ws_size,
                              hipStream_t stream)
{
    const float* s   = (const float*)d_in[0];
    const float* y   = (const float*)d_in[1];
    const float* frc = (const float*)d_in[2];
    float* out = (float*)d_out;
    float* ws  = (float*)d_ws;

    if (ws_size >= (size_t)WS_END(64) * sizeof(float)) {
        // tier 1: KCH=128, 4096 blocks, 4 blocks/CU. No atomics, no memset.
        gram128_kernel<<<dim3(64 * 64), dim3(256), 0, stream>>>(s, y, frc, ws);
        recur_kernel<64, 1><<<dim3(Bh), dim3(256), 0, stream>>>(ws);
    } else if (ws_size >= (size_t)WS_END(32) * sizeof(float)) {
        // tier 2: r5-proven KCH=256 burst gram (slab). No memset.
        gram256_kernel<1><<<dim3(Bh * 32), dim3(256), 0, stream>>>(s, y, frc, ws);
        recur_kernel<32, 1><<<dim3(Bh), dim3(256), 0, stream>>>(ws);
    } else {
        // tier 3: atomic fallback.
        hipMemsetAsync(d_ws, 0, (size_t)WS_ZERO_FLOATS * sizeof(float), stream);
        gram256_kernel<0><<<dim3(Bh * 32), dim3(256), 0, stream>>>(s, y, frc, ws);
        recur_kernel<32, 0><<<dim3(Bh), dim3(256), 0, stream>>>(ws);
    }
    combine_kernel<<<dim3(Bh * 8), dim3(1024), 0, stream>>>(s, y, frc, ws, out);
}